// Round 4
// baseline (373.355 us; speedup 1.0000x reference)
//
#include <hip/hip_runtime.h>
#include <stdint.h>

#define B_ 4
#define H_ 16
#define NQ_ 1024
#define NK_ 1024
#define DM_ 1024
#define DK_ 64

typedef __attribute__((ext_vector_type(8))) short short8;
typedef __attribute__((ext_vector_type(4))) float f32x4;
typedef unsigned short u16;
typedef unsigned int u32;

__device__ __forceinline__ u16 f2bf(float f) {
  u32 u = __builtin_bit_cast(u32, f);
  u32 r = u + 0x7fffu + ((u >> 16) & 1u);
  return (u16)(r >> 16);
}

__device__ __forceinline__ float bf2f(u16 b) {
  u32 u = ((u32)b) << 16;
  return __builtin_bit_cast(float, u);
}

__device__ __forceinline__ short8 ld_short8(const u16* p) {
  return __builtin_bit_cast(short8, *(const int4*)p);
}

// ---------------------------------------------------------------------------
// Mask storage detector: bool (1 byte/elem) vs int32 (4 bytes/elem).
// ---------------------------------------------------------------------------
__global__ void detect_mask_kernel(const unsigned char* __restrict__ m, int* __restrict__ flag) {
  if (threadIdx.x == 0) {
    int f = 0;
    for (int i = 0; i < 256; ++i)
      if ((i & 3) != 0 && m[i] != 0) f = 1;
    *flag = f;  // 1 => byte mask, 0 => int32 mask
  }
}

// ---------------------------------------------------------------------------
// GEMM: C[m][n] = sum_k A[m][k] * W[n][k] + bias[n]   (unchanged)
// ---------------------------------------------------------------------------
__global__ __launch_bounds__(256) void gemm_kernel(
    const float* __restrict__ Aq, const float* __restrict__ Ak, const float* __restrict__ Av,
    const u16* __restrict__ Ao,
    const float* __restrict__ Wq, const float* __restrict__ Wk,
    const float* __restrict__ Wv, const float* __restrict__ Wo,
    const float* __restrict__ bq, const float* __restrict__ bk,
    const float* __restrict__ bv, const float* __restrict__ bo,
    u16* __restrict__ qbuf, u16* __restrict__ kbuf, u16* __restrict__ vTbuf,
    float* __restrict__ outbuf, int mode_base)
{
  const int z = mode_base + (int)blockIdx.z;
  const int n0 = blockIdx.x * 128;
  const int m0 = blockIdx.y * 128;
  const int tid = threadIdx.x;
  const int lane = tid & 63;
  const int wave = tid >> 6;
  const int wm = wave >> 1, wn = wave & 1;

  __shared__ u16 Al[128 * 40];
  __shared__ u16 Bl[128 * 40];

  const float* Af = (z == 0) ? Aq : (z == 1 ? Ak : Av);
  const float* W  = (z == 0) ? Wq : (z == 1 ? Wk : (z == 2 ? Wv : Wo));

  f32x4 acc[4][4];
#pragma unroll
  for (int i = 0; i < 4; ++i)
#pragma unroll
    for (int j = 0; j < 4; ++j) acc[i][j] = (f32x4){0.f, 0.f, 0.f, 0.f};

  float4 arf[4];
  int4   arb[2];
  float4 brf[4];

  auto load_tiles = [&](int ks) {
    const int kk0 = ks * 32;
    if (z < 3) {
#pragma unroll
      for (int c = 0; c < 4; ++c) {
        int chunk = c * 256 + tid;
        arf[c] = *(const float4*)(Af + (size_t)(m0 + (chunk >> 3)) * DM_ + kk0 + (chunk & 7) * 4);
      }
    } else {
#pragma unroll
      for (int c = 0; c < 2; ++c) {
        int chunk = c * 256 + tid;
        arb[c] = *(const int4*)(Ao + (size_t)(m0 + (chunk >> 2)) * DM_ + kk0 + (chunk & 3) * 8);
      }
    }
#pragma unroll
    for (int c = 0; c < 4; ++c) {
      int chunk = c * 256 + tid;
      brf[c] = *(const float4*)(W + (size_t)(n0 + (chunk >> 3)) * DM_ + kk0 + (chunk & 7) * 4);
    }
  };

  auto store_lds = [&]() {
    if (z < 3) {
#pragma unroll
      for (int c = 0; c < 4; ++c) {
        int chunk = c * 256 + tid;
        ushort4 p;
        p.x = f2bf(arf[c].x); p.y = f2bf(arf[c].y); p.z = f2bf(arf[c].z); p.w = f2bf(arf[c].w);
        *(ushort4*)(Al + (chunk >> 3) * 40 + (chunk & 7) * 4) = p;
      }
    } else {
#pragma unroll
      for (int c = 0; c < 2; ++c) {
        int chunk = c * 256 + tid;
        *(int4*)(Al + (chunk >> 2) * 40 + (chunk & 3) * 8) = arb[c];
      }
    }
#pragma unroll
    for (int c = 0; c < 4; ++c) {
      int chunk = c * 256 + tid;
      ushort4 p;
      p.x = f2bf(brf[c].x); p.y = f2bf(brf[c].y); p.z = f2bf(brf[c].z); p.w = f2bf(brf[c].w);
      *(ushort4*)(Bl + (chunk >> 3) * 40 + (chunk & 7) * 4) = p;
    }
  };

  load_tiles(0);
  for (int ks = 0; ks < 32; ++ks) {
    __syncthreads();
    store_lds();
    __syncthreads();
    if (ks < 31) load_tiles(ks + 1);
    short8 afr[4], bfr[4];
#pragma unroll
    for (int i = 0; i < 4; ++i) {
      afr[i] = ld_short8(Al + (wm * 64 + i * 16 + (lane & 15)) * 40 + (lane >> 4) * 8);
      bfr[i] = ld_short8(Bl + (wn * 64 + i * 16 + (lane & 15)) * 40 + (lane >> 4) * 8);
    }
#pragma unroll
    for (int i = 0; i < 4; ++i)
#pragma unroll
      for (int j = 0; j < 4; ++j)
        acc[i][j] = __builtin_amdgcn_mfma_f32_16x16x32_bf16(afr[i], bfr[j], acc[i][j], 0, 0, 0);
  }

  const float* bias = (z == 0) ? bq : (z == 1 ? bk : (z == 2 ? bv : bo));
#pragma unroll
  for (int i = 0; i < 4; ++i) {
    const int token0 = m0 + wm * 64 + i * 16 + (lane >> 4) * 4;
#pragma unroll
    for (int j = 0; j < 4; ++j) {
      const int feat = n0 + wn * 64 + j * 16 + (lane & 15);
      const float bvl = bias[feat];
      if (z == 3) {
#pragma unroll
        for (int r = 0; r < 4; ++r)
          outbuf[(size_t)(token0 + r) * DM_ + feat] = acc[i][j][r] + bvl;
      } else if (z == 2) {
        const int bb = token0 >> 10, t = token0 & 1023;
        const int hh = feat >> 6, d = feat & 63;
        ushort4 p;
        p.x = f2bf(acc[i][j][0] + bvl);
        p.y = f2bf(acc[i][j][1] + bvl);
        p.z = f2bf(acc[i][j][2] + bvl);
        p.w = f2bf(acc[i][j][3] + bvl);
        *(ushort4*)(vTbuf + ((size_t)(bb * H_ + hh) * DK_ + d) * NK_ + t) = p;
      } else {
        u16* dst = (z == 0) ? qbuf : kbuf;
        const int hh = feat >> 6, d = feat & 63;
#pragma unroll
        for (int r = 0; r < 4; ++r) {
          const int token = token0 + r;
          const int bb = token >> 10, t = token & 1023;
          dst[((size_t)(bb * H_ + hh) * NQ_ + t) * DK_ + d] = f2bf(acc[i][j][r] + bvl);
        }
      }
    }
  }
}

// ---------------------------------------------------------------------------
// Attention v4: same structure as v3 but latency-tolerant:
//  - __launch_bounds__(512,4) -> 128 VGPR cap (LDS caps at 2 blocks/CU anyway)
//  - QK^T: depth-8 explicit pipeline of K-fragment loads (64 VGPR in flight)
//  - PV:   depth-8 pipeline (LDS pa + global vf) + dual accumulators
// ---------------------------------------------------------------------------
__global__ __launch_bounds__(512, 4) void attn_kernel(
    const u16* __restrict__ qbuf, const u16* __restrict__ kbuf, const u16* __restrict__ vTbuf,
    const float* __restrict__ aw, const void* __restrict__ maskp, const int* __restrict__ flagp,
    float* __restrict__ attout, u16* __restrict__ obuf)
{
  extern __shared__ char smem[];
  u16* S = (u16*)smem;  // [32][1024] bf16, col swizzled: c ^ ((row&7)<<3)

  const int n = blockIdx.x;
  const int work = (n & 7) * 256 + (n >> 3);  // XCD-chunked swizzle (perf only)
  const int qt = work & 31;
  const int bh = work >> 5;
  const int b = bh >> 4, h = bh & 15;
  const int qbase = qt * 32;
  const int tid = threadIdx.x;
  const int lane = tid & 63;
  const int wave = tid >> 6;
  const int wm = wave >> 2, wn = wave & 3;
  const int hi = lane >> 4;
  const int l15 = lane & 15;
  const int mflag = *flagp;

  const u16* qp = qbuf + ((size_t)bh * NQ_ + qbase + wm * 16 + l15) * DK_ + hi * 8;
  const short8 qf0 = ld_short8(qp);
  const short8 qf1 = ld_short8(qp + 32);

  // ---- QK^T: depth-8 pipelined global K fragment loads ----
  {
    const u16* kb = kbuf + (size_t)bh * NK_ * DK_ + (wn * 16 + l15) * DK_ + hi * 8;
    short8 kf0[8], kf1[8];
#pragma unroll
    for (int p = 0; p < 8; ++p) {
      kf0[p] = ld_short8(kb + p * 64 * DK_);
      kf1[p] = ld_short8(kb + p * 64 * DK_ + 32);
    }
#pragma unroll
    for (int t = 0; t < 16; ++t) {
      f32x4 sacc = (f32x4){0.f, 0.f, 0.f, 0.f};
      sacc = __builtin_amdgcn_mfma_f32_16x16x32_bf16(qf0, kf0[t & 7], sacc, 0, 0, 0);
      sacc = __builtin_amdgcn_mfma_f32_16x16x32_bf16(qf1, kf1[t & 7], sacc, 0, 0, 0);
      if (t + 8 < 16) {
        kf0[t & 7] = ld_short8(kb + (t + 8) * 64 * DK_);
        kf1[t & 7] = ld_short8(kb + (t + 8) * 64 * DK_ + 32);
      }
      const int tk = t * 64 + wn * 16 + l15;
#pragma unroll
      for (int r = 0; r < 4; ++r) {
        const int row = wm * 16 + hi * 4 + r;
        S[row * 1024 + (tk ^ ((row & 7) << 3))] = f2bf(sacc[r]);
      }
    }
  }
  __syncthreads();

  // ---- softmax: one wave per row; each wave does rows wave+8*rr ----
  {
    const int c0 = lane * 8;
    const float scale = 0.125f;
    const float NEGINF = -__builtin_inff();
#pragma unroll
    for (int rr = 0; rr < 4; ++rr) {
      const int row = wave + rr * 8;
      const size_t abase = ((size_t)bh * NQ_ + qbase + row) * (size_t)NK_;
      u16* Srow = S + row * 1024;
      const int swz = (row & 7) << 3;
      f32x4 pe[4];
      float mx = NEGINF;
#pragma unroll
      for (int half = 0; half < 2; ++half) {
        const int c = c0 + half * 512;
        const short8 s8 = ld_short8(Srow + (c ^ swz));
        const f32x4 a0 = *(const f32x4*)(aw + abase + c);
        const f32x4 a1 = *(const f32x4*)(aw + abase + c + 4);
        int k[8];
        if (mflag) {
          uchar4 u0 = *(const uchar4*)((const unsigned char*)maskp + abase + c);
          uchar4 u1 = *(const uchar4*)((const unsigned char*)maskp + abase + c + 4);
          k[0] = u0.x; k[1] = u0.y; k[2] = u0.z; k[3] = u0.w;
          k[4] = u1.x; k[5] = u1.y; k[6] = u1.z; k[7] = u1.w;
        } else {
          int4 u0 = *(const int4*)((const int*)maskp + abase + c);
          int4 u1 = *(const int4*)((const int*)maskp + abase + c + 4);
          k[0] = u0.x; k[1] = u0.y; k[2] = u0.z; k[3] = u0.w;
          k[4] = u1.x; k[5] = u1.y; k[6] = u1.z; k[7] = u1.w;
        }
        f32x4 t0, t1;
        t0[0] = k[0] ? NEGINF : bf2f((u16)s8[0]) * scale * a0[0];
        t0[1] = k[1] ? NEGINF : bf2f((u16)s8[1]) * scale * a0[1];
        t0[2] = k[2] ? NEGINF : bf2f((u16)s8[2]) * scale * a0[2];
        t0[3] = k[3] ? NEGINF : bf2f((u16)s8[3]) * scale * a0[3];
        t1[0] = k[4] ? NEGINF : bf2f((u16)s8[4]) * scale * a1[0];
        t1[1] = k[5] ? NEGINF : bf2f((u16)s8[5]) * scale * a1[1];
        t1[2] = k[6] ? NEGINF : bf2f((u16)s8[6]) * scale * a1[2];
        t1[3] = k[7] ? NEGINF : bf2f((u16)s8[7]) * scale * a1[3];
        pe[2 * half] = t0;
        pe[2 * half + 1] = t1;
        mx = fmaxf(mx, fmaxf(fmaxf(t0[0], t0[1]), fmaxf(t0[2], t0[3])));
        mx = fmaxf(mx, fmaxf(fmaxf(t1[0], t1[1]), fmaxf(t1[2], t1[3])));
      }
#pragma unroll
      for (int o = 32; o >= 1; o >>= 1) mx = fmaxf(mx, __shfl_xor(mx, o));
      float sum = 0.f;
#pragma unroll
      for (int i = 0; i < 4; ++i) {
        f32x4 tv = pe[i];
        tv[0] = __expf(tv[0] - mx); tv[1] = __expf(tv[1] - mx);
        tv[2] = __expf(tv[2] - mx); tv[3] = __expf(tv[3] - mx);
        pe[i] = tv;
        sum += (tv[0] + tv[1]) + (tv[2] + tv[3]);
      }
#pragma unroll
      for (int o = 32; o >= 1; o >>= 1) sum += __shfl_xor(sum, o);
      const float inv = 1.0f / sum;
#pragma unroll
      for (int half = 0; half < 2; ++half) {
        const int c = c0 + half * 512;
        f32x4 t0 = pe[2 * half], t1 = pe[2 * half + 1];
        t0[0] *= inv; t0[1] *= inv; t0[2] *= inv; t0[3] *= inv;
        t1[0] *= inv; t1[1] *= inv; t1[2] *= inv; t1[3] *= inv;
        *(f32x4*)(attout + abase + c) = t0;
        *(f32x4*)(attout + abase + c + 4) = t1;
        short8 p8;
        p8[0] = (short)f2bf(t0[0]); p8[1] = (short)f2bf(t0[1]);
        p8[2] = (short)f2bf(t0[2]); p8[3] = (short)f2bf(t0[3]);
        p8[4] = (short)f2bf(t1[0]); p8[5] = (short)f2bf(t1[1]);
        p8[6] = (short)f2bf(t1[2]); p8[7] = (short)f2bf(t1[3]);
        *(int4*)(Srow + (c ^ swz)) = __builtin_bit_cast(int4, p8);
      }
    }
  }
  __syncthreads();

  // ---- PV: depth-8 pipeline (LDS pa + global vf), dual accumulators ----
  {
    f32x4 oacc0 = (f32x4){0.f, 0.f, 0.f, 0.f};
    f32x4 oacc1 = (f32x4){0.f, 0.f, 0.f, 0.f};
    const int arow = wm * 16 + l15;
    const u16* Sr = S + arow * 1024;
    const int asw = (arow & 7) << 3;
    const int dcol = wn * 16 + l15;
    const u16* vb = vTbuf + ((size_t)bh * DK_ + dcol) * (size_t)NK_ + hi * 8;
    short8 pa[8], vf[8];
#pragma unroll
    for (int p = 0; p < 8; ++p) {
      const int c = p * 32 + hi * 8;
      pa[p] = ld_short8(Sr + (c ^ asw));
      vf[p] = ld_short8(vb + p * 32);
    }
#pragma unroll
    for (int t = 0; t < 32; ++t) {
      if (t & 1)
        oacc1 = __builtin_amdgcn_mfma_f32_16x16x32_bf16(pa[t & 7], vf[t & 7], oacc1, 0, 0, 0);
      else
        oacc0 = __builtin_amdgcn_mfma_f32_16x16x32_bf16(pa[t & 7], vf[t & 7], oacc0, 0, 0, 0);
      if (t + 8 < 32) {
        const int c = (t + 8) * 32 + hi * 8;
        pa[t & 7] = ld_short8(Sr + (c ^ asw));
        vf[t & 7] = ld_short8(vb + (t + 8) * 32);
      }
    }
    const int feat = h * DK_ + dcol;
#pragma unroll
    for (int r = 0; r < 4; ++r) {
      const int q = qbase + wm * 16 + hi * 4 + r;
      obuf[((size_t)b * NQ_ + q) * DM_ + feat] = f2bf(oacc0[r] + oacc1[r]);
    }
  }
}

// ---------------------------------------------------------------------------
extern "C" void kernel_launch(void* const* d_in, const int* in_sizes, int n_in,
                              void* d_out, int out_size, void* d_ws, size_t ws_size,
                              hipStream_t stream)
{
  const float* queries = (const float*)d_in[0];
  const float* keys    = (const float*)d_in[1];
  const float* values  = (const float*)d_in[2];
  const float* aw      = (const float*)d_in[3];
  const void*  maskp   = d_in[4];
  const float* Wq = (const float*)d_in[5];
  const float* bq = (const float*)d_in[6];
  const float* Wk = (const float*)d_in[7];
  const float* bk = (const float*)d_in[8];
  const float* Wv = (const float*)d_in[9];
  const float* bv = (const float*)d_in[10];
  const float* Wo = (const float*)d_in[11];
  const float* bo = (const float*)d_in[12];

  char* ws = (char*)d_ws;
  const size_t NE = (size_t)B_ * H_ * NQ_ * DK_;
  int* flag  = (int*)ws;
  u16* qbuf  = (u16*)(ws + 256);
  u16* kbuf  = qbuf + NE;
  u16* vTbuf = kbuf + NE;
  u16* obuf  = vTbuf + NE;
  if (ws_size < 256 + 8 * NE) return;

  float* outp = (float*)d_out;
  float* attp = outp + (size_t)B_ * NQ_ * DM_;

  detect_mask_kernel<<<1, 64, 0, stream>>>((const unsigned char*)maskp, flag);

  gemm_kernel<<<dim3(8, 32, 3), 256, 0, stream>>>(queries, keys, values, obuf,
      Wq, Wk, Wv, Wo, bq, bk, bv, bo, qbuf, kbuf, vTbuf, outp, 0);

  const int SMEM = 32 * 1024 * 2;  // 64 KB bf16 S strip
  hipFuncSetAttribute(reinterpret_cast<const void*>(attn_kernel),
                      hipFuncAttributeMaxDynamicSharedMemorySize, SMEM);
  attn_kernel<<<dim3(2048), 512, SMEM, stream>>>(qbuf, kbuf, vTbuf, aw, maskp, flag,
                                                 attp, obuf);

  gemm_kernel<<<dim3(8, 32, 1), 256, 0, stream>>>(queries, keys, values, obuf,
      Wq, Wk, Wv, Wo, bq, bk, bv, bo, qbuf, kbuf, vTbuf, outp, 3);
}

// Round 5
// 367.919 us; speedup vs baseline: 1.0148x; 1.0148x over previous
//
#include <hip/hip_runtime.h>
#include <stdint.h>

#define B_ 4
#define H_ 16
#define NQ_ 1024
#define NK_ 1024
#define DM_ 1024
#define DK_ 64

typedef __attribute__((ext_vector_type(8))) short short8;
typedef __attribute__((ext_vector_type(4))) float f32x4;
typedef unsigned short u16;
typedef unsigned int u32;

__device__ __forceinline__ u16 f2bf(float f) {
  u32 u = __builtin_bit_cast(u32, f);
  u32 r = u + 0x7fffu + ((u >> 16) & 1u);
  return (u16)(r >> 16);
}

__device__ __forceinline__ float bf2f(u16 b) {
  u32 u = ((u32)b) << 16;
  return __builtin_bit_cast(float, u);
}

__device__ __forceinline__ short8 ld_short8(const u16* p) {
  return __builtin_bit_cast(short8, *(const int4*)p);
}

// ---------------------------------------------------------------------------
// Mask storage detector: bool (1 byte/elem) vs int32 (4 bytes/elem).
// ---------------------------------------------------------------------------
__global__ void detect_mask_kernel(const unsigned char* __restrict__ m, int* __restrict__ flag) {
  if (threadIdx.x == 0) {
    int f = 0;
    for (int i = 0; i < 256; ++i)
      if ((i & 3) != 0 && m[i] != 0) f = 1;
    *flag = f;  // 1 => byte mask, 0 => int32 mask
  }
}

// ---------------------------------------------------------------------------
// GEMM: C[m][n] = sum_k A[m][k] * W[n][k] + bias[n]   (unchanged)
// ---------------------------------------------------------------------------
__global__ __launch_bounds__(256) void gemm_kernel(
    const float* __restrict__ Aq, const float* __restrict__ Ak, const float* __restrict__ Av,
    const u16* __restrict__ Ao,
    const float* __restrict__ Wq, const float* __restrict__ Wk,
    const float* __restrict__ Wv, const float* __restrict__ Wo,
    const float* __restrict__ bq, const float* __restrict__ bk,
    const float* __restrict__ bv, const float* __restrict__ bo,
    u16* __restrict__ qbuf, u16* __restrict__ kbuf, u16* __restrict__ vTbuf,
    float* __restrict__ outbuf, int mode_base)
{
  const int z = mode_base + (int)blockIdx.z;
  const int n0 = blockIdx.x * 128;
  const int m0 = blockIdx.y * 128;
  const int tid = threadIdx.x;
  const int lane = tid & 63;
  const int wave = tid >> 6;
  const int wm = wave >> 1, wn = wave & 1;

  __shared__ u16 Al[128 * 40];
  __shared__ u16 Bl[128 * 40];

  const float* Af = (z == 0) ? Aq : (z == 1 ? Ak : Av);
  const float* W  = (z == 0) ? Wq : (z == 1 ? Wk : (z == 2 ? Wv : Wo));

  f32x4 acc[4][4];
#pragma unroll
  for (int i = 0; i < 4; ++i)
#pragma unroll
    for (int j = 0; j < 4; ++j) acc[i][j] = (f32x4){0.f, 0.f, 0.f, 0.f};

  float4 arf[4];
  int4   arb[2];
  float4 brf[4];

  auto load_tiles = [&](int ks) {
    const int kk0 = ks * 32;
    if (z < 3) {
#pragma unroll
      for (int c = 0; c < 4; ++c) {
        int chunk = c * 256 + tid;
        arf[c] = *(const float4*)(Af + (size_t)(m0 + (chunk >> 3)) * DM_ + kk0 + (chunk & 7) * 4);
      }
    } else {
#pragma unroll
      for (int c = 0; c < 2; ++c) {
        int chunk = c * 256 + tid;
        arb[c] = *(const int4*)(Ao + (size_t)(m0 + (chunk >> 2)) * DM_ + kk0 + (chunk & 3) * 8);
      }
    }
#pragma unroll
    for (int c = 0; c < 4; ++c) {
      int chunk = c * 256 + tid;
      brf[c] = *(const float4*)(W + (size_t)(n0 + (chunk >> 3)) * DM_ + kk0 + (chunk & 7) * 4);
    }
  };

  auto store_lds = [&]() {
    if (z < 3) {
#pragma unroll
      for (int c = 0; c < 4; ++c) {
        int chunk = c * 256 + tid;
        ushort4 p;
        p.x = f2bf(arf[c].x); p.y = f2bf(arf[c].y); p.z = f2bf(arf[c].z); p.w = f2bf(arf[c].w);
        *(ushort4*)(Al + (chunk >> 3) * 40 + (chunk & 7) * 4) = p;
      }
    } else {
#pragma unroll
      for (int c = 0; c < 2; ++c) {
        int chunk = c * 256 + tid;
        *(int4*)(Al + (chunk >> 2) * 40 + (chunk & 3) * 8) = arb[c];
      }
    }
#pragma unroll
    for (int c = 0; c < 4; ++c) {
      int chunk = c * 256 + tid;
      ushort4 p;
      p.x = f2bf(brf[c].x); p.y = f2bf(brf[c].y); p.z = f2bf(brf[c].z); p.w = f2bf(brf[c].w);
      *(ushort4*)(Bl + (chunk >> 3) * 40 + (chunk & 7) * 4) = p;
    }
  };

  load_tiles(0);
  for (int ks = 0; ks < 32; ++ks) {
    __syncthreads();
    store_lds();
    __syncthreads();
    if (ks < 31) load_tiles(ks + 1);
    short8 afr[4], bfr[4];
#pragma unroll
    for (int i = 0; i < 4; ++i) {
      afr[i] = ld_short8(Al + (wm * 64 + i * 16 + (lane & 15)) * 40 + (lane >> 4) * 8);
      bfr[i] = ld_short8(Bl + (wn * 64 + i * 16 + (lane & 15)) * 40 + (lane >> 4) * 8);
    }
#pragma unroll
    for (int i = 0; i < 4; ++i)
#pragma unroll
      for (int j = 0; j < 4; ++j)
        acc[i][j] = __builtin_amdgcn_mfma_f32_16x16x32_bf16(afr[i], bfr[j], acc[i][j], 0, 0, 0);
  }

  const float* bias = (z == 0) ? bq : (z == 1 ? bk : (z == 2 ? bv : bo));
#pragma unroll
  for (int i = 0; i < 4; ++i) {
    const int token0 = m0 + wm * 64 + i * 16 + (lane >> 4) * 4;
#pragma unroll
    for (int j = 0; j < 4; ++j) {
      const int feat = n0 + wn * 64 + j * 16 + (lane & 15);
      const float bvl = bias[feat];
      if (z == 3) {
#pragma unroll
        for (int r = 0; r < 4; ++r)
          outbuf[(size_t)(token0 + r) * DM_ + feat] = acc[i][j][r] + bvl;
      } else if (z == 2) {
        const int bb = token0 >> 10, t = token0 & 1023;
        const int hh = feat >> 6, d = feat & 63;
        ushort4 p;
        p.x = f2bf(acc[i][j][0] + bvl);
        p.y = f2bf(acc[i][j][1] + bvl);
        p.z = f2bf(acc[i][j][2] + bvl);
        p.w = f2bf(acc[i][j][3] + bvl);
        *(ushort4*)(vTbuf + ((size_t)(bb * H_ + hh) * DK_ + d) * NK_ + t) = p;
      } else {
        u16* dst = (z == 0) ? qbuf : kbuf;
        const int hh = feat >> 6, d = feat & 63;
#pragma unroll
        for (int r = 0; r < 4; ++r) {
          const int token = token0 + r;
          const int bb = token >> 10, t = token & 1023;
          dst[((size_t)(bb * H_ + hh) * NQ_ + t) * DK_ + d] = f2bf(acc[i][j][r] + bvl);
        }
      }
    }
  }
}

// ---------------------------------------------------------------------------
// Attention v5: 16 q-rows/block -> 32 KB LDS -> 4 blocks/CU (100% occupancy).
// QK^T: each wave owns 16 cols per iter (8 iters). Softmax: one wave per row,
// 2 rows/wave. PV: 2-way k-split across wave halves, fp32 partial combine via
// LDS (aliased onto dead S strip).
// ---------------------------------------------------------------------------
__global__ __launch_bounds__(512, 8) void attn_kernel(
    const u16* __restrict__ qbuf, const u16* __restrict__ kbuf, const u16* __restrict__ vTbuf,
    const float* __restrict__ aw, const void* __restrict__ maskp, const int* __restrict__ flagp,
    float* __restrict__ attout, u16* __restrict__ obuf)
{
  __shared__ u16 S[16 * 1024];  // 32 KB bf16 strip, col swizzle: c ^ ((row&7)<<3)

  const int n = blockIdx.x;
  const int work = (n & 7) * 512 + (n >> 3);  // XCD-chunked swizzle (perf only)
  const int qt = work & 63;
  const int bh = work >> 6;
  const int b = bh >> 4, h = bh & 15;
  const int qbase = qt * 16;
  const int tid = threadIdx.x;
  const int lane = tid & 63;
  const int wave = tid >> 6;   // 0..7
  const int hi = lane >> 4;
  const int l15 = lane & 15;
  const int mflag = *flagp;

  // Q fragments: rows qbase + l15 (same for all waves; L1 broadcast)
  const u16* qp = qbuf + ((size_t)bh * NQ_ + qbase + l15) * DK_ + hi * 8;
  const short8 qf0 = ld_short8(qp);
  const short8 qf1 = ld_short8(qp + 32);

  // ---- QK^T: wave owns cols t*128 + wave*16 ----
  {
    const u16* kb = kbuf + (size_t)bh * NK_ * DK_;
#pragma unroll
    for (int t = 0; t < 8; ++t) {
      const int tk = t * 128 + wave * 16 + l15;
      const short8 kf0 = ld_short8(kb + tk * DK_ + hi * 8);
      const short8 kf1 = ld_short8(kb + tk * DK_ + 32 + hi * 8);
      f32x4 sacc = (f32x4){0.f, 0.f, 0.f, 0.f};
      sacc = __builtin_amdgcn_mfma_f32_16x16x32_bf16(qf0, kf0, sacc, 0, 0, 0);
      sacc = __builtin_amdgcn_mfma_f32_16x16x32_bf16(qf1, kf1, sacc, 0, 0, 0);
#pragma unroll
      for (int r = 0; r < 4; ++r) {
        const int row = hi * 4 + r;
        S[row * 1024 + (tk ^ ((row & 7) << 3))] = f2bf(sacc[r]);
      }
    }
  }
  __syncthreads();

  // ---- softmax: one wave per row; rows wave and wave+8 ----
  {
    const int c0 = lane * 8;
    const float scale = 0.125f;
    const float NEGINF = -__builtin_inff();
#pragma unroll
    for (int rr = 0; rr < 2; ++rr) {
      const int row = wave + rr * 8;
      const size_t abase = ((size_t)bh * NQ_ + qbase + row) * (size_t)NK_;
      u16* Srow = S + row * 1024;
      const int swz = (row & 7) << 3;
      f32x4 pe[4];
      float mx = NEGINF;
#pragma unroll
      for (int half = 0; half < 2; ++half) {
        const int c = c0 + half * 512;
        const short8 s8 = ld_short8(Srow + (c ^ swz));
        const f32x4 a0 = *(const f32x4*)(aw + abase + c);
        const f32x4 a1 = *(const f32x4*)(aw + abase + c + 4);
        int k[8];
        if (mflag) {
          uchar4 u0 = *(const uchar4*)((const unsigned char*)maskp + abase + c);
          uchar4 u1 = *(const uchar4*)((const unsigned char*)maskp + abase + c + 4);
          k[0] = u0.x; k[1] = u0.y; k[2] = u0.z; k[3] = u0.w;
          k[4] = u1.x; k[5] = u1.y; k[6] = u1.z; k[7] = u1.w;
        } else {
          int4 u0 = *(const int4*)((const int*)maskp + abase + c);
          int4 u1 = *(const int4*)((const int*)maskp + abase + c + 4);
          k[0] = u0.x; k[1] = u0.y; k[2] = u0.z; k[3] = u0.w;
          k[4] = u1.x; k[5] = u1.y; k[6] = u1.z; k[7] = u1.w;
        }
        f32x4 t0, t1;
        t0[0] = k[0] ? NEGINF : bf2f((u16)s8[0]) * scale * a0[0];
        t0[1] = k[1] ? NEGINF : bf2f((u16)s8[1]) * scale * a0[1];
        t0[2] = k[2] ? NEGINF : bf2f((u16)s8[2]) * scale * a0[2];
        t0[3] = k[3] ? NEGINF : bf2f((u16)s8[3]) * scale * a0[3];
        t1[0] = k[4] ? NEGINF : bf2f((u16)s8[4]) * scale * a1[0];
        t1[1] = k[5] ? NEGINF : bf2f((u16)s8[5]) * scale * a1[1];
        t1[2] = k[6] ? NEGINF : bf2f((u16)s8[6]) * scale * a1[2];
        t1[3] = k[7] ? NEGINF : bf2f((u16)s8[7]) * scale * a1[3];
        pe[2 * half] = t0;
        pe[2 * half + 1] = t1;
        mx = fmaxf(mx, fmaxf(fmaxf(t0[0], t0[1]), fmaxf(t0[2], t0[3])));
        mx = fmaxf(mx, fmaxf(fmaxf(t1[0], t1[1]), fmaxf(t1[2], t1[3])));
      }
#pragma unroll
      for (int o = 32; o >= 1; o >>= 1) mx = fmaxf(mx, __shfl_xor(mx, o));
      float sum = 0.f;
#pragma unroll
      for (int i = 0; i < 4; ++i) {
        f32x4 tv = pe[i];
        tv[0] = __expf(tv[0] - mx); tv[1] = __expf(tv[1] - mx);
        tv[2] = __expf(tv[2] - mx); tv[3] = __expf(tv[3] - mx);
        pe[i] = tv;
        sum += (tv[0] + tv[1]) + (tv[2] + tv[3]);
      }
#pragma unroll
      for (int o = 32; o >= 1; o >>= 1) sum += __shfl_xor(sum, o);
      const float inv = 1.0f / sum;
#pragma unroll
      for (int half = 0; half < 2; ++half) {
        const int c = c0 + half * 512;
        f32x4 t0 = pe[2 * half], t1 = pe[2 * half + 1];
        t0[0] *= inv; t0[1] *= inv; t0[2] *= inv; t0[3] *= inv;
        t1[0] *= inv; t1[1] *= inv; t1[2] *= inv; t1[3] *= inv;
        *(f32x4*)(attout + abase + c) = t0;
        *(f32x4*)(attout + abase + c + 4) = t1;
        short8 p8;
        p8[0] = (short)f2bf(t0[0]); p8[1] = (short)f2bf(t0[1]);
        p8[2] = (short)f2bf(t0[2]); p8[3] = (short)f2bf(t0[3]);
        p8[4] = (short)f2bf(t1[0]); p8[5] = (short)f2bf(t1[1]);
        p8[6] = (short)f2bf(t1[2]); p8[7] = (short)f2bf(t1[3]);
        *(int4*)(Srow + (c ^ swz)) = __builtin_bit_cast(int4, p8);
      }
    }
  }
  __syncthreads();

  // ---- PV: 2-way k-split; waves (kh=wave>>2) cover k in [kh*512, kh*512+512)
  {
    const int kh = wave >> 2;
    const int j = wave & 3;
    const int arow = l15;
    const u16* Sr = S + arow * 1024;
    const int asw = (arow & 7) << 3;
    const int dcol = j * 16 + l15;
    const u16* vb = vTbuf + ((size_t)bh * DK_ + dcol) * (size_t)NK_;
    f32x4 oacc = (f32x4){0.f, 0.f, 0.f, 0.f};
#pragma unroll
    for (int t = 0; t < 16; ++t) {
      const int c = kh * 512 + t * 32 + hi * 8;
      const short8 pa = ld_short8(Sr + (c ^ asw));
      const short8 vf = ld_short8(vb + c);
      oacc = __builtin_amdgcn_mfma_f32_16x16x32_bf16(pa, vf, oacc, 0, 0, 0);
    }
    __syncthreads();                 // all P reads complete
    float* Pbuf = (float*)S;         // 16 x 64 fp32 partials (4 KB, aliases S)
    if (kh == 1) {
#pragma unroll
      for (int r = 0; r < 4; ++r)
        Pbuf[(hi * 4 + r) * 64 + dcol] = oacc[r];
    }
    __syncthreads();
    if (kh == 0) {
      const int feat = h * DK_ + dcol;
#pragma unroll
      for (int r = 0; r < 4; ++r) {
        const int row = hi * 4 + r;
        obuf[((size_t)b * NQ_ + qbase + row) * DM_ + feat] =
            f2bf(oacc[r] + Pbuf[row * 64 + dcol]);
      }
    }
  }
}

// ---------------------------------------------------------------------------
extern "C" void kernel_launch(void* const* d_in, const int* in_sizes, int n_in,
                              void* d_out, int out_size, void* d_ws, size_t ws_size,
                              hipStream_t stream)
{
  const float* queries = (const float*)d_in[0];
  const float* keys    = (const float*)d_in[1];
  const float* values  = (const float*)d_in[2];
  const float* aw      = (const float*)d_in[3];
  const void*  maskp   = d_in[4];
  const float* Wq = (const float*)d_in[5];
  const float* bq = (const float*)d_in[6];
  const float* Wk = (const float*)d_in[7];
  const float* bk = (const float*)d_in[8];
  const float* Wv = (const float*)d_in[9];
  const float* bv = (const float*)d_in[10];
  const float* Wo = (const float*)d_in[11];
  const float* bo = (const float*)d_in[12];

  char* ws = (char*)d_ws;
  const size_t NE = (size_t)B_ * H_ * NQ_ * DK_;
  int* flag  = (int*)ws;
  u16* qbuf  = (u16*)(ws + 256);
  u16* kbuf  = qbuf + NE;
  u16* vTbuf = kbuf + NE;
  u16* obuf  = vTbuf + NE;
  if (ws_size < 256 + 8 * NE) return;

  float* outp = (float*)d_out;
  float* attp = outp + (size_t)B_ * NQ_ * DM_;

  detect_mask_kernel<<<1, 64, 0, stream>>>((const unsigned char*)maskp, flag);

  gemm_kernel<<<dim3(8, 32, 3), 256, 0, stream>>>(queries, keys, values, obuf,
      Wq, Wk, Wv, Wo, bq, bk, bv, bo, qbuf, kbuf, vTbuf, outp, 0);

  attn_kernel<<<dim3(4096), 512, 0, stream>>>(qbuf, kbuf, vTbuf, aw, maskp, flag,
                                              attp, obuf);

  gemm_kernel<<<dim3(8, 32, 1), 256, 0, stream>>>(queries, keys, values, obuf,
      Wq, Wk, Wv, Wo, bq, bk, bv, bo, qbuf, kbuf, vTbuf, outp, 3);
}